// Round 9
// baseline (592.454 us; speedup 1.0000x reference)
//
#include <hip/hip_runtime.h>
#include <hip/hip_bf16.h>

// Problem constants (from reference)
#define N_NODES 50000
#define D_FEAT  128
#define N_EDGES 600000
#define HIDDEN  256
#define K_DIM   256   // 2*D_FEAT

#define BUCKET   64    // edge slots per node; P(Poisson(12) > 64) ~ 1e-30
#define M_TILE   32
#define NTILES   1563  // ceil(50000/32)

typedef __attribute__((ext_vector_type(8))) short bf16x8;   // 8 bf16 = 4 VGPRs
typedef __attribute__((ext_vector_type(4))) float f32x4;    // MFMA acc

__device__ __forceinline__ unsigned short f32_to_bf16(float f) {
    unsigned int u = __float_as_uint(f);
    unsigned int r = (u + 0x7fffu + ((u >> 16) & 1u)) >> 16;  // RNE
    return (unsigned short)r;
}
__device__ __forceinline__ float bf16_to_f32(unsigned short u) {
    return __uint_as_float(((unsigned int)u) << 16);
}
__device__ __forceinline__ unsigned int pack_bf16x2(float lo, float hi) {
    return (unsigned int)f32_to_bf16(lo) | ((unsigned int)f32_to_bf16(hi) << 16);
}

// ---------------------------------------------------------------------------
// K1: bucket fill (receiver-grouped u16 sender lists) + nodes f32 -> packed
//     bf16 conversion + W repack into MFMA-B-fragment order
//     Wp[kt][n][quad][j], k = kt*32 + quad*8 + j.
// ---------------------------------------------------------------------------
__global__ __launch_bounds__(256) void build_conv_repack(
    const int* __restrict__ senders,
    const int* __restrict__ receivers,
    const float* __restrict__ nodes,
    const float* __restrict__ W,
    unsigned int* __restrict__ cnt,        // [N] pre-zeroed
    unsigned short* __restrict__ edges16,  // [N*BUCKET]
    unsigned int* __restrict__ nb,         // [N*64] packed bf16x2
    unsigned short* __restrict__ Wp) {     // [65536]
    const int gid = blockIdx.x * 256 + threadIdx.x;
    const int gsz = gridDim.x * 256;
    for (int e = gid; e < N_EDGES; e += gsz) {
        int r = receivers[e];
        unsigned int slot = atomicAdd(&cnt[r], 1u);
        if (slot < (unsigned int)BUCKET)
            edges16[(size_t)r * BUCKET + slot] = (unsigned short)senders[e];
    }
    for (int p = gid; p < N_NODES * 64; p += gsz) {
        const float2 v = *(const float2*)(nodes + (size_t)p * 2);
        nb[p] = pack_bf16x2(v.x, v.y);
    }
    for (int t = gid; t < 65536; t += gsz) {
        int kt = t >> 13;
        int n  = (t >> 5) & 255;
        int q  = (t >> 3) & 3;
        int j  = t & 7;
        int k  = kt * 32 + q * 8 + j;
        Wp[t] = f32_to_bf16(W[k * 256 + n]);
    }
}

// ---------------------------------------------------------------------------
// K2: fused edge-parallel gather-mean + concat + MFMA GEMM + bias + relu.
// Tile = 32 nodes x 256 hidden, 256 threads (4 waves).
// Phase A: flatten the tile's bucket edges into LDS (row<<16|sender), then
//   each wave walks the flat list 16 edges deep: 2 ushort bf16 loads per edge
//   (features lane, lane+64 -> 2x128B coalesced; 32 loads = 64 lines in
//   flight) + 2 ds_add_f32 into the f32 LDS accumulator (2-way banks, free).
// Phase B: A-frags k<128 from f32 hacc (ds_read_b128 x2 + cvt), k>=128 from
//   bf16 self tile; B-frags from Wp; 2x4 mfma_f32_16x16x32_bf16.
// hacc stride 132 f32 (528B = 33x16, aligned; banks 2-way).
// hs   stride  68 u32 (272B = 17x16, aligned; banks 2-way).
// ---------------------------------------------------------------------------
__global__ __launch_bounds__(256, 4) void gather_mean_gemm(
    const unsigned int* __restrict__ nb,
    const unsigned int* __restrict__ cnt,
    const unsigned short* __restrict__ edges16,
    const unsigned short* __restrict__ Wp,
    const float* __restrict__ bias,
    float* __restrict__ out) {
    __shared__ __align__(16) float hacc[M_TILE * 132];        // 16.9 KB
    __shared__ __align__(16) unsigned int shared2[M_TILE * 68]; // 8.7 KB: eflat then hs
    __shared__ unsigned int cn[M_TILE];
    __shared__ unsigned int pref[M_TILE + 1];
    __shared__ float invdeg[M_TILE];

    const int m0   = blockIdx.x * M_TILE;
    const int tid  = threadIdx.x;
    const int wave = tid >> 6;
    const int lane = tid & 63;

    // ---- zero accumulator, load per-row counts ----
    for (int i = tid; i < M_TILE * 132; i += 256) hacc[i] = 0.f;
    if (tid < M_TILE) {
        int m = m0 + tid;
        unsigned int c = 0;
        if (m < N_NODES) {
            c = cnt[m];
            if (c > (unsigned int)BUCKET) c = (unsigned int)BUCKET;
        }
        cn[tid] = c;
        invdeg[tid] = 1.0f / fmaxf((float)c, 1.0f);
    }
    __syncthreads();
    if (tid == 0) {
        unsigned int run = 0;
        for (int r = 0; r < M_TILE; r++) { pref[r] = run; run += cn[r]; }
        pref[M_TILE] = run;
    }
    __syncthreads();

    // ---- fill flat edge list (8 threads per row) ----
    unsigned int* eflat = shared2;   // <= 32*64 = 2048 <= 2176 capacity
    {
        int r  = tid >> 3, st = tid & 7;
        unsigned int c = cn[r], base = pref[r];
        size_t eb = (size_t)(m0 + r) * BUCKET;
        for (unsigned int s = st; s < c; s += 8)
            eflat[base + s] = ((unsigned int)r << 16) | edges16[eb + s];
    }
    __syncthreads();

    // ---- edge loop: 16-deep per wave ----
    const unsigned short* nb16 = (const unsigned short*)nb;
    const int total = pref[M_TILE];
    for (int base = wave * 16; base < total; base += 64) {
        int nEdge = total - base; if (nEdge > 16) nEdge = 16;
        unsigned int desc[16];
        unsigned short flo[16], fhi[16];
        #pragma unroll
        for (int j = 0; j < 16; j++) {
            if (j < nEdge) {
                desc[j] = eflat[base + j];
                size_t sa = (size_t)(desc[j] & 0xffffu) * 128;
                flo[j] = nb16[sa + lane];
                fhi[j] = nb16[sa + 64 + lane];
            }
        }
        #pragma unroll
        for (int j = 0; j < 16; j++) {
            if (j < nEdge) {
                int r = (int)(desc[j] >> 16);
                atomicAdd(&hacc[r * 132 + lane],      bf16_to_f32(flo[j]));
                atomicAdd(&hacc[r * 132 + 64 + lane], bf16_to_f32(fhi[j]));
            }
        }
    }
    __syncthreads();

    // ---- normalize h_e; repurpose shared2 as bf16 self tile ----
    for (int i = tid; i < M_TILE * 128; i += 256) {
        int r = i >> 7, c = i & 127;
        hacc[r * 132 + c] *= invdeg[r];
    }
    for (int i = tid; i < M_TILE * 64; i += 256) {
        int r = i >> 6, c = i & 63;
        int m = m0 + r;
        shared2[r * 68 + c] = (m < N_NODES) ? nb[(size_t)m * 64 + c] : 0u;
    }
    __syncthreads();

    // ---- Phase B: MFMA GEMM ----
    const unsigned short* hs16 = (const unsigned short*)shared2;
    const int nbase = wave * 64;
    const int rsel  = lane & 15;   // n (B/D) or m (A) within 16
    const int quad  = lane >> 4;   // k-group / row-group selector

    f32x4 acc[2][4] = {};

    #pragma unroll
    for (int kt = 0; kt < 8; kt++) {
        bf16x8 a[2], bw[4];
        #pragma unroll
        for (int mt = 0; mt < 2; mt++) {
            int row = mt * 16 + rsel;
            if (kt < 4) {
                const float* pa = &hacc[row * 132 + kt * 32 + quad * 8];
                f32x4 vlo = *(const f32x4*)pa;        // ds_read_b128
                f32x4 vhi = *(const f32x4*)(pa + 4);  // ds_read_b128
                union { bf16x8 v; unsigned short u[8]; } tmp;
                #pragma unroll
                for (int j = 0; j < 4; j++) {
                    tmp.u[j]     = f32_to_bf16(vlo[j]);
                    tmp.u[4 + j] = f32_to_bf16(vhi[j]);
                }
                a[mt] = tmp.v;
            } else {
                a[mt] = *(const bf16x8*)
                    &hs16[row * 136 + (kt - 4) * 32 + quad * 8];
            }
        }
        #pragma unroll
        for (int nt = 0; nt < 4; nt++) {
            int n = nbase + nt * 16 + rsel;
            bw[nt] = *(const bf16x8*)&Wp[kt * 8192 + n * 32 + quad * 8];
        }
        #pragma unroll
        for (int mt = 0; mt < 2; mt++)
            #pragma unroll
            for (int nt = 0; nt < 4; nt++)
                acc[mt][nt] = __builtin_amdgcn_mfma_f32_16x16x32_bf16(
                    a[mt], bw[nt], acc[mt][nt], 0, 0, 0);
    }

    // epilogue: bias + relu, f32 store.  C/D: col(n)=lane&15, row(m)=quad*4+reg
    #pragma unroll
    for (int nt = 0; nt < 4; nt++) {
        int n = nbase + nt * 16 + rsel;
        float bn = bias[n];
        #pragma unroll
        for (int mt = 0; mt < 2; mt++) {
            #pragma unroll
            for (int r = 0; r < 4; r++) {
                int m = m0 + mt * 16 + quad * 4 + r;
                if (m < N_NODES) {
                    float v = acc[mt][nt][r] + bn;
                    out[(size_t)m * HIDDEN + n] = fmaxf(v, 0.0f);
                }
            }
        }
    }
}

// ---------------------------------------------------------------------------
extern "C" void kernel_launch(void* const* d_in, const int* in_sizes, int n_in,
                              void* d_out, int out_size, void* d_ws, size_t ws_size,
                              hipStream_t stream) {
    const float* nodes     = (const float*)d_in[0];   // f32 [N,128]
    const int*   senders   = (const int*)d_in[1];     // [E]
    const int*   receivers = (const int*)d_in[2];     // [E]
    const float* W         = (const float*)d_in[3];   // f32 [256,256]
    const float* bias      = (const float*)d_in[4];   // f32 [256]
    float*       out       = (float*)d_out;           // f32 [N,256]

    // workspace layout (~19.5 MB total)
    unsigned int*   cnt     = (unsigned int*)d_ws;                  // [N] (zeroed)
    unsigned short* edges16 = (unsigned short*)(cnt + N_NODES);     // [N*BUCKET] u16
    unsigned int*   nb      = (unsigned int*)(edges16 + (size_t)N_NODES * BUCKET); // [N*64]
    unsigned short* Wp      = (unsigned short*)(nb + (size_t)N_NODES * 64);        // [65536]

    hipMemsetAsync(cnt, 0, (size_t)N_NODES * sizeof(unsigned int), stream);

    build_conv_repack<<<dim3(4096), dim3(256), 0, stream>>>(
        senders, receivers, nodes, W, cnt, edges16, nb, Wp);

    gather_mean_gemm<<<dim3(NTILES), dim3(256), 0, stream>>>(
        nb, cnt, edges16, Wp, bias, out);
}

// Round 10
// 182.136 us; speedup vs baseline: 3.2528x; 3.2528x over previous
//
#include <hip/hip_runtime.h>
#include <hip/hip_bf16.h>

// Problem constants (from reference)
#define N_NODES 50000
#define D_FEAT  128
#define N_EDGES 600000
#define HIDDEN  256
#define K_DIM   256   // 2*D_FEAT

#define BUCKET   64      // edge slots per node; P(Poisson(12) > 64) ~ 1e-30
#define ZERO_ROW 50000   // dedicated all-zero node row (pad target)
#define M_TILE   32
#define NTILES   1563    // ceil(50000/32)
#define H_STRIDE 264     // u16 units; 132 u32 units

typedef __attribute__((ext_vector_type(8))) short bf16x8;   // 8 bf16 = 4 VGPRs
typedef __attribute__((ext_vector_type(4))) float f32x4;    // MFMA acc

__device__ __forceinline__ unsigned short f32_to_bf16(float f) {
    unsigned int u = __float_as_uint(f);
    unsigned int r = (u + 0x7fffu + ((u >> 16) & 1u)) >> 16;  // RNE
    return (unsigned short)r;
}
__device__ __forceinline__ unsigned int pack_bf16x2(float lo, float hi) {
    return (unsigned int)f32_to_bf16(lo) | ((unsigned int)f32_to_bf16(hi) << 16);
}
__device__ __forceinline__ float bf_lo(unsigned int v) {
    return __uint_as_float(v << 16);
}
__device__ __forceinline__ float bf_hi(unsigned int v) {
    return __uint_as_float(v & 0xffff0000u);
}

// ---------------------------------------------------------------------------
// K1: bucket fill (receiver-grouped u16 sender ids) + nodes f32 -> packed
//     bf16 (incl. zeroed pad row ZERO_ROW) + W repack into B-fragment order
//     Wp[kt][n][quad][j], k = kt*32 + quad*8 + j.
// ---------------------------------------------------------------------------
__global__ __launch_bounds__(256) void build_conv_repack(
    const int* __restrict__ senders,
    const int* __restrict__ receivers,
    const float* __restrict__ nodes,
    const float* __restrict__ W,
    unsigned short* __restrict__ edges16,  // [N*BUCKET]
    unsigned int* __restrict__ cnt,        // [N] pre-zeroed
    unsigned int* __restrict__ nb,         // [(N+1)*64] packed bf16x2
    unsigned short* __restrict__ Wp) {     // [65536]
    const int gid = blockIdx.x * 256 + threadIdx.x;
    const int gsz = gridDim.x * 256;
    for (int e = gid; e < N_EDGES; e += gsz) {
        int r = receivers[e];
        unsigned int slot = atomicAdd(&cnt[r], 1u);
        if (slot < (unsigned int)BUCKET)
            edges16[(size_t)r * BUCKET + slot] = (unsigned short)senders[e];
    }
    for (int p = gid; p < N_NODES * 64; p += gsz) {
        const float2 v = *(const float2*)(nodes + (size_t)p * 2);
        nb[p] = pack_bf16x2(v.x, v.y);
    }
    if (gid < 64) nb[(size_t)ZERO_ROW * 64 + gid] = 0u;   // zero pad row
    for (int t = gid; t < 65536; t += gsz) {
        int kt = t >> 13;
        int n  = (t >> 5) & 255;
        int q  = (t >> 3) & 3;
        int j  = t & 7;
        int k  = kt * 32 + q * 8 + j;
        Wp[t] = f32_to_bf16(W[k * 256 + n]);
    }
}

// ---------------------------------------------------------------------------
// K2: fused bucket-gather mean + concat + MFMA GEMM + bias + relu.
// Tile = 32 nodes x 256 hidden, 256 threads (4 waves); wave owns 8 rows.
// Phase A (per row): trip count padded to x16; 16 UNCONDITIONAL bf16x2 row
//   loads per iteration (pad slots -> ZERO_ROW via wave-uniform selects) =
//   16 independent 256B row-gathers in flight. f32 accumulate in 8 chains,
//   bf16 pack into LDS h (stride 264 u16: 2-way banks, free per m136).
// Phase B: 2x4 tiles of mfma_f32_16x16x32_bf16 over K=256 (R3/R5/R8-verified).
// ---------------------------------------------------------------------------
__global__ __launch_bounds__(256) void gather_mean_gemm(
    const unsigned int* __restrict__ nb,
    const unsigned int* __restrict__ cnt,
    const unsigned short* __restrict__ edges16,
    const unsigned short* __restrict__ Wp,
    const float* __restrict__ bias,
    float* __restrict__ out) {
    __shared__ __align__(16) unsigned int h32[M_TILE * (H_STRIDE / 2)];

    const int m0   = blockIdx.x * M_TILE;
    const int tid  = threadIdx.x;
    const int wave = tid >> 6;
    const int lane = tid & 63;

    // ---- Phase A: padded 16-deep bucket gather + mean + self ----
    for (int i = 0; i < 8; i++) {
        int row = wave * 8 + i;
        int m   = m0 + row;
        float s0 = 0.f, s1 = 0.f, p0 = 0.f, p1 = 0.f;
        float q0 = 0.f, q1 = 0.f, r0 = 0.f, r1 = 0.f;
        unsigned int selfp = 0u;
        unsigned int c = 0;
        if (m < N_NODES) {
            c = cnt[m];
            if (c > (unsigned int)BUCKET) c = (unsigned int)BUCKET;
            const unsigned int* ep =
                (const unsigned int*)(edges16 + (size_t)m * BUCKET);
            unsigned int cp = (c + 15u) & ~15u;
            for (unsigned int s = 0; s < cp; s += 16) {
                // 8 u32 words = 16 candidate ids (bucket row always readable)
                unsigned int w0 = ep[(s >> 1) + 0], w1 = ep[(s >> 1) + 1];
                unsigned int w2 = ep[(s >> 1) + 2], w3 = ep[(s >> 1) + 3];
                unsigned int w4 = ep[(s >> 1) + 4], w5 = ep[(s >> 1) + 5];
                unsigned int w6 = ep[(s >> 1) + 6], w7 = ep[(s >> 1) + 7];
                // wave-uniform pad selects -> ZERO_ROW (no divergence)
                unsigned int id0  = (s + 0  < c) ? (w0 & 0xffffu) : ZERO_ROW;
                unsigned int id1  = (s + 1  < c) ? (w0 >> 16)     : ZERO_ROW;
                unsigned int id2  = (s + 2  < c) ? (w1 & 0xffffu) : ZERO_ROW;
                unsigned int id3  = (s + 3  < c) ? (w1 >> 16)     : ZERO_ROW;
                unsigned int id4  = (s + 4  < c) ? (w2 & 0xffffu) : ZERO_ROW;
                unsigned int id5  = (s + 5  < c) ? (w2 >> 16)     : ZERO_ROW;
                unsigned int id6  = (s + 6  < c) ? (w3 & 0xffffu) : ZERO_ROW;
                unsigned int id7  = (s + 7  < c) ? (w3 >> 16)     : ZERO_ROW;
                unsigned int id8  = (s + 8  < c) ? (w4 & 0xffffu) : ZERO_ROW;
                unsigned int id9  = (s + 9  < c) ? (w4 >> 16)     : ZERO_ROW;
                unsigned int id10 = (s + 10 < c) ? (w5 & 0xffffu) : ZERO_ROW;
                unsigned int id11 = (s + 11 < c) ? (w5 >> 16)     : ZERO_ROW;
                unsigned int id12 = (s + 12 < c) ? (w6 & 0xffffu) : ZERO_ROW;
                unsigned int id13 = (s + 13 < c) ? (w6 >> 16)     : ZERO_ROW;
                unsigned int id14 = (s + 14 < c) ? (w7 & 0xffffu) : ZERO_ROW;
                unsigned int id15 = (s + 15 < c) ? (w7 >> 16)     : ZERO_ROW;
                // 16 UNCONDITIONAL independent row loads (4B/lane each)
                unsigned int v0  = nb[(size_t)id0  * 64 + lane];
                unsigned int v1  = nb[(size_t)id1  * 64 + lane];
                unsigned int v2  = nb[(size_t)id2  * 64 + lane];
                unsigned int v3  = nb[(size_t)id3  * 64 + lane];
                unsigned int v4  = nb[(size_t)id4  * 64 + lane];
                unsigned int v5  = nb[(size_t)id5  * 64 + lane];
                unsigned int v6  = nb[(size_t)id6  * 64 + lane];
                unsigned int v7  = nb[(size_t)id7  * 64 + lane];
                unsigned int v8  = nb[(size_t)id8  * 64 + lane];
                unsigned int v9  = nb[(size_t)id9  * 64 + lane];
                unsigned int v10 = nb[(size_t)id10 * 64 + lane];
                unsigned int v11 = nb[(size_t)id11 * 64 + lane];
                unsigned int v12 = nb[(size_t)id12 * 64 + lane];
                unsigned int v13 = nb[(size_t)id13 * 64 + lane];
                unsigned int v14 = nb[(size_t)id14 * 64 + lane];
                unsigned int v15 = nb[(size_t)id15 * 64 + lane];
                // 8 accumulation chains (4 lo + 4 hi)
                s0 += bf_lo(v0);  s1 += bf_hi(v0);  p0 += bf_lo(v1);  p1 += bf_hi(v1);
                q0 += bf_lo(v2);  q1 += bf_hi(v2);  r0 += bf_lo(v3);  r1 += bf_hi(v3);
                s0 += bf_lo(v4);  s1 += bf_hi(v4);  p0 += bf_lo(v5);  p1 += bf_hi(v5);
                q0 += bf_lo(v6);  q1 += bf_hi(v6);  r0 += bf_lo(v7);  r1 += bf_hi(v7);
                s0 += bf_lo(v8);  s1 += bf_hi(v8);  p0 += bf_lo(v9);  p1 += bf_hi(v9);
                q0 += bf_lo(v10); q1 += bf_hi(v10); r0 += bf_lo(v11); r1 += bf_hi(v11);
                s0 += bf_lo(v12); s1 += bf_hi(v12); p0 += bf_lo(v13); p1 += bf_hi(v13);
                q0 += bf_lo(v14); q1 += bf_hi(v14); r0 += bf_lo(v15); r1 += bf_hi(v15);
            }
            selfp = nb[(size_t)m * 64 + lane];
        }
        float inv = 1.0f / fmaxf((float)c, 1.0f);
        float a0 = (s0 + p0 + q0 + r0) * inv;
        float a1 = (s1 + p1 + q1 + r1) * inv;
        h32[row * (H_STRIDE / 2) + lane]      = pack_bf16x2(a0, a1);
        h32[row * (H_STRIDE / 2) + 64 + lane] = selfp;
    }
    __syncthreads();

    // ---- Phase B: MFMA GEMM (R8-verified) ----
    const unsigned short* h = (const unsigned short*)h32;
    const int nbase = wave * 64;
    const int rsel  = lane & 15;   // n (B/D) or m (A) within 16
    const int quad  = lane >> 4;   // k-group / row-group selector

    f32x4 acc[2][4] = {};

    for (int kk = 0; kk < K_DIM; kk += 32) {
        bf16x8 a[2], bw[4];
        #pragma unroll
        for (int mt = 0; mt < 2; mt++) {
            const unsigned short* pa =
                &h[(mt * 16 + rsel) * H_STRIDE + kk + quad * 8];
            a[mt] = *(const bf16x8*)pa;   // ds_read_b128
        }
        int kt = kk >> 5;
        #pragma unroll
        for (int nt = 0; nt < 4; nt++) {
            int n = nbase + nt * 16 + rsel;
            bw[nt] = *(const bf16x8*)&Wp[kt * 8192 + n * 32 + quad * 8];
        }
        #pragma unroll
        for (int mt = 0; mt < 2; mt++)
            #pragma unroll
            for (int nt = 0; nt < 4; nt++)
                acc[mt][nt] = __builtin_amdgcn_mfma_f32_16x16x32_bf16(
                    a[mt], bw[nt], acc[mt][nt], 0, 0, 0);
    }

    // epilogue: bias + relu, f32 store.  C/D: col(n)=lane&15, row(m)=quad*4+reg
    #pragma unroll
    for (int nt = 0; nt < 4; nt++) {
        int n = nbase + nt * 16 + rsel;
        float bn = bias[n];
        #pragma unroll
        for (int mt = 0; mt < 2; mt++) {
            #pragma unroll
            for (int r = 0; r < 4; r++) {
                int m = m0 + mt * 16 + quad * 4 + r;
                if (m < N_NODES) {
                    float v = acc[mt][nt][r] + bn;
                    out[(size_t)m * HIDDEN + n] = fmaxf(v, 0.0f);
                }
            }
        }
    }
}

// ---------------------------------------------------------------------------
extern "C" void kernel_launch(void* const* d_in, const int* in_sizes, int n_in,
                              void* d_out, int out_size, void* d_ws, size_t ws_size,
                              hipStream_t stream) {
    const float* nodes     = (const float*)d_in[0];   // f32 [N,128]
    const int*   senders   = (const int*)d_in[1];     // [E]
    const int*   receivers = (const int*)d_in[2];     // [E]
    const float* W         = (const float*)d_in[3];   // f32 [256,256]
    const float* bias      = (const float*)d_in[4];   // f32 [256]
    float*       out       = (float*)d_out;           // f32 [N,256]

    // workspace layout (~19.5 MB). edges16 first -> 128B-aligned bucket rows.
    unsigned short* edges16 = (unsigned short*)d_ws;                 // [N*BUCKET]
    unsigned int*   cnt     = (unsigned int*)(edges16 + (size_t)N_NODES * BUCKET); // [N]
    unsigned int*   nb      = cnt + N_NODES;                         // [(N+1)*64]
    unsigned short* Wp      = (unsigned short*)(nb + (size_t)(N_NODES + 1) * 64); // [65536]

    hipMemsetAsync(cnt, 0, (size_t)N_NODES * sizeof(unsigned int), stream);

    build_conv_repack<<<dim3(1024), dim3(256), 0, stream>>>(
        senders, receivers, nodes, W, edges16, cnt, nb, Wp);

    gather_mean_gemm<<<dim3(NTILES), dim3(256), 0, stream>>>(
        nb, cnt, edges16, Wp, bias, out);
}